// Round 20
// baseline (55.853 us; speedup 1.0000x reference)
//
#include <hip/hip_runtime.h>

// Resample 48k -> 10k via MFMA, LDS-FREE: up=5, down=24, 481-tap FIR.
// y[5k+d] = sum_c Tap[c][d]*x[24k-48+c]; Y(16x16) = A(16x128)*B(128x16),
// 4x mfma_f32_16x16x32_bf16. A[r][c]=bf16(x[24(k0+r)-48+c]).
//
// R20: A fragments loaded DIRECTLY from global (2x dwordx4 per K-chunk per
// lane) + in-register cvt_pk -> NO LDS, NO BARRIERS, fully independent waves
// (the wave-count law that survived all 19 rounds, at minimum serial work).
// Lanes of one load instruction alias cachelines (span ~1.6kB) -> coalescer
// serves unique lines; redundancy costs only cvt_pk (VALU is spare).
// Unlike R6 (30kB/thread windows, 6x overfetch): footprint ~2kB/wave burst,
// cross-tile halo 8%.
// B constant in 16 VGPRs (prep-packed, L2-hot 4KB). C/D col=l&15(=d),
// row=(l>>4)*4+reg [m89]. R18 (LDS-staged) = 43.5us fallback.

#define NIN    1440000
#define NOUTR  300000
#define NROWS  32
#define KTOT   60000
#define NCHUNK 938               // 64-k chunks per row
#define S      4                 // chunks per block
#define NBX    235               // ceil(938/4)
#define TAPN   600

typedef __attribute__((ext_vector_type(8))) short short8v;
typedef __attribute__((ext_vector_type(4))) float float4v;

__device__ __forceinline__ unsigned short f2b(float f) {
    unsigned u = __builtin_bit_cast(unsigned, f);
    u += 0x7fff + ((u >> 16) & 1);                 // RNE
    return (unsigned short)(u >> 16);
}

// Bpk[(m*64+l)*8+j] = bf16( Tap[c=32m+8*(l>>4)+j][d=l&15] ), 4KB in ws.
__global__ void prep_taps_kernel(const float* __restrict__ h,
                                 unsigned short* __restrict__ Bpk) {
    int i = blockIdx.x * blockDim.x + threadIdx.x;     // 0..2047
    if (i < 2048) {
        int j = i & 7, l = (i >> 3) & 63, m = i >> 9;
        int d = l & 15, q = l >> 4;
        int c = 32 * m + 8 * q + j;
        int t = 24 * d + 480 - 5 * c;
        float v = (d < 5 && t >= 0 && t <= 480) ? h[t] * 5.0f : 0.0f;
        Bpk[i] = f2b(v);
    }
}

__device__ __forceinline__ short8v pack_frag(const float4& a, const float4& b) {
    unsigned r0, r1, r2, r3;
    asm("v_cvt_pk_bf16_f32 %0, %1, %2" : "=v"(r0) : "v"(a.x), "v"(a.y));
    asm("v_cvt_pk_bf16_f32 %0, %1, %2" : "=v"(r1) : "v"(a.z), "v"(a.w));
    asm("v_cvt_pk_bf16_f32 %0, %1, %2" : "=v"(r2) : "v"(b.x), "v"(b.y));
    asm("v_cvt_pk_bf16_f32 %0, %1, %2" : "=v"(r3) : "v"(b.z), "v"(b.w));
    return __builtin_bit_cast(short8v, make_uint4(r0, r1, r2, r3));
}

__global__ __launch_bounds__(256, 7) void resample_kernel(
    const float* __restrict__ x, const unsigned short* __restrict__ Bpk,
    float* __restrict__ y)
{
    const int tid  = threadIdx.x;
    const int lane = tid & 63;
    const int wv   = tid >> 6;                     // 0..3: 16-k group per wave
    const int row  = blockIdx.y;
    const int cb   = blockIdx.x * S;
    const float* __restrict__ xr = x + (size_t)row * NIN;

    // B fragments: constant across all tiles (L2-hot 4KB table).
    const short8v B0 = *reinterpret_cast<const short8v*>(Bpk + (0 * 64 + lane) * 8);
    const short8v B1 = *reinterpret_cast<const short8v*>(Bpk + (1 * 64 + lane) * 8);
    const short8v B2 = *reinterpret_cast<const short8v*>(Bpk + (2 * 64 + lane) * 8);
    const short8v B3 = *reinterpret_cast<const short8v*>(Bpk + (3 * 64 + lane) * 8);

    const int r = lane & 15, q = lane >> 4;
    const int loff = 24 * (16 * wv + r) + 8 * q;   // lane's window offset

    for (int s = 0; s < S; ++s) {
        const int ct = cb + s;
        if (ct >= NCHUNK) break;                   // uniform
        const int g0 = 1536 * ct - 48;
        const int gl = g0 + loff;                  // lane's A window base

        float4 p0, p1, p2, p3, p4, p5, p6, p7;     // 8 floats per K-chunk x4
        if (g0 >= 0 && g0 + 1632 <= NIN) {         // interior fast path
            const float4* __restrict__ p = reinterpret_cast<const float4*>(xr + gl);
            p0 = p[0]; p1 = p[1];                  // K-chunk 0: c in [0,32)
            p2 = p[8]; p3 = p[9];                  // K-chunk 1 (+32 floats)
            p4 = p[16]; p5 = p[17];                // K-chunk 2
            p6 = p[24]; p7 = p[25];                // K-chunk 3
        } else {                                   // first/last chunk only
            auto ld8 = [&](int base, float4& a, float4& b) {
                float v[8];
                #pragma unroll
                for (int j = 0; j < 8; ++j) {
                    const int g = base + j;
                    v[j] = ((unsigned)g < NIN) ? xr[g] : 0.0f;
                }
                a = make_float4(v[0], v[1], v[2], v[3]);
                b = make_float4(v[4], v[5], v[6], v[7]);
            };
            ld8(gl,      p0, p1);
            ld8(gl + 32, p2, p3);
            ld8(gl + 64, p4, p5);
            ld8(gl + 96, p6, p7);
        }

        const short8v A0 = pack_frag(p0, p1);
        const short8v A1 = pack_frag(p2, p3);
        const short8v A2 = pack_frag(p4, p5);
        const short8v A3 = pack_frag(p6, p7);

        float4v acc = {0.f, 0.f, 0.f, 0.f};
        acc = __builtin_amdgcn_mfma_f32_16x16x32_bf16(A0, B0, acc, 0, 0, 0);
        acc = __builtin_amdgcn_mfma_f32_16x16x32_bf16(A1, B1, acc, 0, 0, 0);
        acc = __builtin_amdgcn_mfma_f32_16x16x32_bf16(A2, B2, acc, 0, 0, 0);
        acc = __builtin_amdgcn_mfma_f32_16x16x32_bf16(A3, B3, acc, 0, 0, 0);

        // C/D: col=lane&15 (=d), row=(lane>>4)*4+j (=k-local).
        const int d = lane & 15;
        if (d < 5) {
            const int kbase = 64 * ct + 16 * wv + 4 * q;
            float* __restrict__ yr = y + (size_t)row * NOUTR;
            #pragma unroll
            for (int j = 0; j < 4; ++j) {
                const int k = kbase + j;
                if (k < KTOT) yr[5 * (size_t)k + d] = acc[j];
            }
        }
    }
}

extern "C" void kernel_launch(void* const* d_in, const int* in_sizes, int n_in,
                              void* d_out, int out_size, void* d_ws, size_t ws_size,
                              hipStream_t stream) {
    const float* x = (const float*)d_in[0];
    const float* h = (const float*)d_in[1];        // 481 taps
    float* y = (float*)d_out;                      // 32 x 300000 f32
    unsigned short* Bpk = (unsigned short*)d_ws;   // 4KB packed B fragments

    prep_taps_kernel<<<8, 256, 0, stream>>>(h, Bpk);
    dim3 grid(NBX, NROWS);                         // 235 x 32, 256-thr blocks
    resample_kernel<<<grid, 256, 0, stream>>>(x, Bpk, y);
}

// Round 21
// 48.699 us; speedup vs baseline: 1.1469x; 1.1469x over previous
//
#include <hip/hip_runtime.h>

// Resample 48k -> 10k via MFMA: up=5, down=24, 481-tap FIR.
// y[5k+d] = sum_{c=0..119} Tap[c][d]*x[24k-48+c], Tap[c][d]=5h[24d+480-5c]
// Y(16k x 16, 5 cols used) = A(16x128)*B(128x16), 4x mfma_f32_16x16x32_bf16.
// A[r][c]=bf16(x[24(k0+r)-48+c]): lane fragment = 8 contiguous bf16 = ONE
// ds_read_b128. B constant in 16 VGPRs (prep-packed, L2-hot 4KB).
// C/D: col=l&15 (=d), row=(l>>4)*4+reg (=k-local) [m89].
//
// R21: S=1 SINGLE-SHOT BLOCKS (one 64-k tile per block, 30016 blocks).
// R18/R19 were ~8%-issue, 44%-HBM -> latency-bound; the S=8 per-block serial
// {stage->barrier->compute->drain} chain was the untested inherited binder.
// Session lever that always worked = more independent parallel units.
// Block turnover staggers phases across the CU; store-drain overlaps other
// blocks' compute. Cost: halo fetch 0.8%->6.25% (~+5MB), B reload per block
// (L2-hot). R18 = 43.5us fallback.

#define NIN    1440000
#define NOUTR  300000
#define NROWS  32
#define KTOT   60000
#define NCHUNK 938               // 64-k tiles per row = blocks per row
#define TILE_E 1632              // x-elems per tile
#define TILE_P 1648              // +16 zero pad (A reads c<=127 -> idx<=1639)
#define NT8    204               // staging threads (8 floats each)

typedef __attribute__((ext_vector_type(8))) short short8v;
typedef __attribute__((ext_vector_type(4))) float float4v;

__device__ __forceinline__ unsigned short f2b(float f) {
    unsigned u = __builtin_bit_cast(unsigned, f);
    u += 0x7fff + ((u >> 16) & 1);                 // RNE
    return (unsigned short)(u >> 16);
}

// Bpk[(m*64+l)*8+j] = bf16( Tap[c=32m+8*(l>>4)+j][d=l&15] ), 4KB in ws.
__global__ void prep_taps_kernel(const float* __restrict__ h,
                                 unsigned short* __restrict__ Bpk) {
    int i = blockIdx.x * blockDim.x + threadIdx.x;     // 0..2047
    if (i < 2048) {
        int j = i & 7, l = (i >> 3) & 63, m = i >> 9;
        int d = l & 15, q = l >> 4;
        int c = 32 * m + 8 * q + j;
        int t = 24 * d + 480 - 5 * c;
        float v = (d < 5 && t >= 0 && t <= 480) ? h[t] * 5.0f : 0.0f;
        Bpk[i] = f2b(v);
    }
}

__global__ __launch_bounds__(256, 7) void resample_kernel(
    const float* __restrict__ x, const unsigned short* __restrict__ Bpk,
    float* __restrict__ y)
{
    __shared__ short ldsb[TILE_P];                 // bf16 bits
    const int tid  = threadIdx.x;
    const int lane = tid & 63;
    const int wv   = tid >> 6;                     // 0..3: 16-k group per wave
    const int row  = blockIdx.y;
    const int ct   = blockIdx.x;                   // this block's 64-k tile
    const float* __restrict__ xr = x + (size_t)row * NIN;
    const int g0 = 1536 * ct - 48;                 // 16B-aligned

    // B fragments: 4 global b128 loads (L2-hot 4KB), issued first.
    const short8v B0 = *reinterpret_cast<const short8v*>(Bpk + (0 * 64 + lane) * 8);
    const short8v B1 = *reinterpret_cast<const short8v*>(Bpk + (1 * 64 + lane) * 8);
    const short8v B2 = *reinterpret_cast<const short8v*>(Bpk + (2 * 64 + lane) * 8);
    const short8v B3 = *reinterpret_cast<const short8v*>(Bpk + (3 * 64 + lane) * 8);

    if (tid < TILE_P - TILE_E) ldsb[TILE_E + tid] = 0;   // zero pad: 0*NaN guard

    // Stage tile: 8 floats/thread -> 4x cvt_pk -> one ds_write_b128.
    if (tid < NT8) {
        float4 pa, pb;
        if (g0 >= 0 && g0 + TILE_E <= NIN) {       // interior fast path
            const float4* __restrict__ p = reinterpret_cast<const float4*>(xr + g0);
            pa = p[2 * tid];
            pb = p[2 * tid + 1];
        } else {                                   // first/last block only
            float v[8];
            #pragma unroll
            for (int j = 0; j < 8; ++j) {
                const int g = g0 + 8 * tid + j;
                v[j] = ((unsigned)g < NIN) ? xr[g] : 0.0f;
            }
            pa = make_float4(v[0], v[1], v[2], v[3]);
            pb = make_float4(v[4], v[5], v[6], v[7]);
        }
        unsigned r0, r1, r2, r3;
        asm("v_cvt_pk_bf16_f32 %0, %1, %2" : "=v"(r0) : "v"(pa.x), "v"(pa.y));
        asm("v_cvt_pk_bf16_f32 %0, %1, %2" : "=v"(r1) : "v"(pa.z), "v"(pa.w));
        asm("v_cvt_pk_bf16_f32 %0, %1, %2" : "=v"(r2) : "v"(pb.x), "v"(pb.y));
        asm("v_cvt_pk_bf16_f32 %0, %1, %2" : "=v"(r3) : "v"(pb.z), "v"(pb.w));
        *reinterpret_cast<uint4*>(&ldsb[8 * tid]) = make_uint4(r0, r1, r2, r3);
    }
    __syncthreads();

    // A fragments: row r=lane&15, K-pos = 32m + 8q + j.
    const int r = lane & 15, q = lane >> 4;
    const short* __restrict__ ap = &ldsb[24 * (16 * wv + r) + 8 * q];
    const short8v A0 = *reinterpret_cast<const short8v*>(ap);
    const short8v A1 = *reinterpret_cast<const short8v*>(ap + 32);
    const short8v A2 = *reinterpret_cast<const short8v*>(ap + 64);
    const short8v A3 = *reinterpret_cast<const short8v*>(ap + 96);

    float4v acc = {0.f, 0.f, 0.f, 0.f};
    acc = __builtin_amdgcn_mfma_f32_16x16x32_bf16(A0, B0, acc, 0, 0, 0);
    acc = __builtin_amdgcn_mfma_f32_16x16x32_bf16(A1, B1, acc, 0, 0, 0);
    acc = __builtin_amdgcn_mfma_f32_16x16x32_bf16(A2, B2, acc, 0, 0, 0);
    acc = __builtin_amdgcn_mfma_f32_16x16x32_bf16(A3, B3, acc, 0, 0, 0);

    // C/D: col=lane&15 (=d), row=(lane>>4)*4+j (=k-local).
    const int d = lane & 15;
    if (d < 5) {
        const int kbase = 64 * ct + 16 * wv + 4 * q;
        float* __restrict__ yr = y + (size_t)row * NOUTR;
        #pragma unroll
        for (int j = 0; j < 4; ++j) {
            const int k = kbase + j;
            if (k < KTOT) yr[5 * (size_t)k + d] = acc[j];
        }
    }
}

extern "C" void kernel_launch(void* const* d_in, const int* in_sizes, int n_in,
                              void* d_out, int out_size, void* d_ws, size_t ws_size,
                              hipStream_t stream) {
    const float* x = (const float*)d_in[0];
    const float* h = (const float*)d_in[1];        // 481 taps
    float* y = (float*)d_out;                      // 32 x 300000 f32
    unsigned short* Bpk = (unsigned short*)d_ws;   // 4KB packed B fragments

    prep_taps_kernel<<<8, 256, 0, stream>>>(h, Bpk);
    dim3 grid(NCHUNK, NROWS);                      // 938 x 32 single-shot blocks
    resample_kernel<<<grid, 256, 0, stream>>>(x, Bpk, y);
}

// Round 22
// 41.791 us; speedup vs baseline: 1.3365x; 1.1653x over previous
//
#include <hip/hip_runtime.h>

// Resample 48k -> 10k via MFMA, 3-phase-set packing.
// y[5k+d] = sum_{cc=0..119} Tap[cc][d]*x[24k-48+cc], Tap[cc][d]=5h[24d+480-5cc]
// Column j=5D+d (D=0..2, 15 of 16 used), row r covers k=k0+3r+D:
//   Y[r][5D+d] = sum_c A[r][c]*B[c][5D+d],  A[r][c]=bf16(x[24(k0+3r)-48+c]),
//   B[c][5D+d]=Tap[c-24D][d] (zero outside). K=192 -> 6x mfma_f32_16x16x32_bf16.
// Wave-tile = 48 k / 240 outputs (vs 16 k / 80 in R18): ds_read 2x/k down,
// MFMA 2x down, stores 3x down (60/64 lanes), barrier gens 3x down.
// A layout (HW-verified R18): row=lane&15, k=32m+8(lane>>4)+j.
// C/D [m89]: col=lane&15, row=4*(lane>>4)+reg -> k = kgen+48wv+12q+3*reg+D.

#define NIN    1440000
#define NOUTR  300000
#define NROWS  32
#define KTOT   60000
#define KB     192               // k per gen (4 waves x 48)
#define GENS   313               // ceil(60000/192)
#define S      4                 // gens per block
#define NBX    79                // ceil(313/4)
#define TILE_E 4752              // 24*(KB-1) + 168 window floats
#define NU8    594               // 8-float staging units (4752/8)

typedef __attribute__((ext_vector_type(8))) short short8v;
typedef __attribute__((ext_vector_type(4))) float float4v;

__device__ __forceinline__ unsigned short f2b(float f) {
    unsigned u = __builtin_bit_cast(unsigned, f);
    u += 0x7fff + ((u >> 16) & 1);                 // RNE
    return (unsigned short)(u >> 16);
}

// Bpk[(m*64+l)*8+j] = bf16( B[c=32m+8*(l>>4)+j][col=l&15] ), 6KB in ws.
__global__ void prep_taps_kernel(const float* __restrict__ h,
                                 unsigned short* __restrict__ Bpk) {
    int i = blockIdx.x * blockDim.x + threadIdx.x;     // 0..3071
    if (i < 3072) {
        int j = i & 7, l = (i >> 3) & 63, m = i >> 9;  // m 0..5
        int col = l & 15, q = l >> 4;
        int c = 32 * m + 8 * q + j;
        int D = col / 5, d = col - 5 * D;
        int t = 24 * d + 480 - 5 * (c - 24 * D);
        float v = (col < 15 && t >= 0 && t <= 480) ? h[t] * 5.0f : 0.0f;
        Bpk[i] = f2b(v);
    }
}

__global__ __launch_bounds__(256, 5) void resample_kernel(
    const float* __restrict__ x, const unsigned short* __restrict__ Bpk,
    float* __restrict__ y)
{
    __shared__ __align__(16) short ldsb[TILE_E];   // bf16 bits, 9504 B
    const int tid  = threadIdx.x;
    const int lane = tid & 63;
    const int wv   = tid >> 6;                     // 0..3: 48-k group per wave
    const int row  = blockIdx.y;
    const int gb   = blockIdx.x * S;               // first gen
    const int n    = min(S, GENS - gb);            // block-uniform, >=1
    const float* __restrict__ xr = x + (size_t)row * NIN;

    // B fragments: 6 x b128 (L2-hot 6KB table), constant across gens.
    short8v Bf[6];
    #pragma unroll
    for (int m = 0; m < 6; ++m)
        Bf[m] = *reinterpret_cast<const short8v*>(Bpk + (m * 64 + lane) * 8);

    const int q = lane >> 4, r = lane & 15;
    const int col = r;                             // C/D col = lane&15
    const int D = col / 5, d = col - 5 * D;        // phase-set, phase
    const int aoff = 1152 * wv + 72 * r + 8 * q;   // lane's A base (el)

    for (int s = 0; s < n; ++s) {
        const int kgen = KB * (gb + s);            // gen's base k
        const int gg = 24 * kgen - 48;             // tile start; 16B-aligned
        __syncthreads();                           // prior gen's reads done

        if (gg >= 0 && gg + TILE_E <= NIN) {       // interior fast path
            const float4* __restrict__ p = reinterpret_cast<const float4*>(xr + gg);
            auto stu = [&](int u) {                // 8 floats -> b128 write
                const float4 pa = p[2 * u], pb = p[2 * u + 1];
                unsigned r0, r1, r2, r3;
                asm("v_cvt_pk_bf16_f32 %0, %1, %2" : "=v"(r0) : "v"(pa.x), "v"(pa.y));
                asm("v_cvt_pk_bf16_f32 %0, %1, %2" : "=v"(r1) : "v"(pa.z), "v"(pa.w));
                asm("v_cvt_pk_bf16_f32 %0, %1, %2" : "=v"(r2) : "v"(pb.x), "v"(pb.y));
                asm("v_cvt_pk_bf16_f32 %0, %1, %2" : "=v"(r3) : "v"(pb.z), "v"(pb.w));
                *reinterpret_cast<uint4*>(&ldsb[8 * u]) = make_uint4(r0, r1, r2, r3);
            };
            stu(tid);
            stu(tid + 256);
            if (tid < NU8 - 512) stu(tid + 512);
        } else {                                   // first/last gens only
            auto stu = [&](int u) {
                float v[8];
                #pragma unroll
                for (int j = 0; j < 8; ++j) {
                    const int g = gg + 8 * u + j;
                    v[j] = ((unsigned)g < NIN) ? xr[g] : 0.0f;
                }
                unsigned r0, r1, r2, r3;
                asm("v_cvt_pk_bf16_f32 %0, %1, %2" : "=v"(r0) : "v"(v[0]), "v"(v[1]));
                asm("v_cvt_pk_bf16_f32 %0, %1, %2" : "=v"(r1) : "v"(v[2]), "v"(v[3]));
                asm("v_cvt_pk_bf16_f32 %0, %1, %2" : "=v"(r2) : "v"(v[4]), "v"(v[5]));
                asm("v_cvt_pk_bf16_f32 %0, %1, %2" : "=v"(r3) : "v"(v[6]), "v"(v[7]));
                *reinterpret_cast<uint4*>(&ldsb[8 * u]) = make_uint4(r0, r1, r2, r3);
            };
            stu(tid);
            stu(tid + 256);
            if (tid < NU8 - 512) stu(tid + 512);
        }
        __syncthreads();                           // tile staged

        // A fragments + MFMA chain over K=192.
        const short* __restrict__ ap = &ldsb[aoff];
        float4v acc = {0.f, 0.f, 0.f, 0.f};
        #pragma unroll
        for (int m = 0; m < 6; ++m) {
            const short8v A = *reinterpret_cast<const short8v*>(ap + 32 * m);
            acc = __builtin_amdgcn_mfma_f32_16x16x32_bf16(A, Bf[m], acc, 0, 0, 0);
        }

        // Stores: k = kgen + 48wv + 12q + 3*reg + D, phase d.
        if (col < 15) {
            const int kw = kgen + 48 * wv + 12 * q + D;
            float* __restrict__ yr = y + (size_t)row * NOUTR;
            #pragma unroll
            for (int jj = 0; jj < 4; ++jj) {
                const int k = kw + 3 * jj;
                if (k < KTOT) yr[5 * (size_t)k + d] = acc[jj];
            }
        }
    }
}

extern "C" void kernel_launch(void* const* d_in, const int* in_sizes, int n_in,
                              void* d_out, int out_size, void* d_ws, size_t ws_size,
                              hipStream_t stream) {
    const float* x = (const float*)d_in[0];
    const float* h = (const float*)d_in[1];        // 481 taps
    float* y = (float*)d_out;                      // 32 x 300000 f32
    unsigned short* Bpk = (unsigned short*)d_ws;   // 6KB packed B fragments

    prep_taps_kernel<<<12, 256, 0, stream>>>(h, Bpk);
    dim3 grid(NBX, NROWS);                         // 79 x 32, 256-thr blocks
    resample_kernel<<<grid, 256, 0, stream>>>(x, Bpk, y);
}